// Round 14
// baseline (65.668 us; speedup 1.0000x reference)
//
#include <hip/hip_runtime.h>
#include <hip/hip_fp16.h>

#define HH 256
#define WW 256
#define CC 64
#define BB 2
#define KK2 9
#define HWSZ (HH * WW)

#define TH 16
#define TW 32
#define NR 26                 // window rows [h0-5, h0+20]
#define NC 44                 // window cols [w0-5, w0+38]
#define NRC (NR * NC)         // 1144 slots
#define PSTRIDE (NRC + 1)     // +1 quad pad between planes
#define NTHR 512

struct __align__(16) H8 { __half2 h[4]; };   // 8 halves = 16 B

// ---------------- transpose+convert: x[b][c][h][w] f32 -> xT[b][h][w][c] f16 ----------------
__global__ __launch_bounds__(256, 4) void transpose_nchw_to_nhwc_f16(
    const float* __restrict__ x, __half* __restrict__ xT)
{
    __shared__ float tile[CC][65];
    const int row = blockIdx.x;
    const int h   = row & (HH - 1);
    const int b   = row >> 8;
    const int w0  = blockIdx.y * 64;
    const int lw  = threadIdx.x & 63;
    const int lr  = threadIdx.x >> 6;

    const float* xp = x + (size_t)b * CC * HWSZ + h * WW + w0;
#pragma unroll
    for (int p = 0; p < 16; ++p) {
        int c = p * 4 + lr;
        tile[c][lw] = xp[(size_t)c * HWSZ + lw];
    }
    __syncthreads();

    __half2* xo2 = (__half2*)(xT + ((size_t)(b * HH + h) * WW + w0) * CC);
    const int m  = threadIdx.x & 31;
    const int w8 = threadIdx.x >> 5;
#pragma unroll
    for (int q = 0; q < 8; ++q) {
        int wl = w8 + q * 8;
        float lo = tile[2 * m][wl];
        float hi = tile[2 * m + 1][wl];
        xo2[wl * 32 + m] = __floats2half2_rn(lo, hi);
    }
}

// ---------------- main: LDS-staged bilinear gather, 512-thread blocks ----------------
// 512 blocks x 512 threads. Block = 16x32 px x 32 ch (c-half). Window 26x44 fp16
// in LDS (73.3 KB, 2 blocks/CU = 16 waves/CU). Param loads issued before staging
// (L2 latency drains under staging + barrier). k-loop: ds_read_b128 + v_pk_fma_f16.
__global__ __launch_bounds__(512, 4) void dcn_lds(
    const __half* __restrict__ xT,
    const float* __restrict__ offset,
    const float* __restrict__ mask,
    const float* __restrict__ weight,
    float* __restrict__ out)
{
    __shared__ __half smem[4 * PSTRIDE * 8];   // 73280 B

    const int nb = BB * (HH / TH) * (WW / TW) * 2;   // 512
    int flat = blockIdx.x;
    int sb = (flat & 7) * (nb >> 3) + (flat >> 3);   // XCD-chunked, row-band sequential
    const int half = sb & 1;
    const int tw   = (sb >> 1) & 7;
    const int th   = (sb >> 4) & 15;
    const int b    = sb >> 8;

    const int h0 = th * TH, w0 = tw * TW;
    const int r0 = h0 - 5, c0 = w0 - 5;
    const int r1 = r0 + NR - 1, c1 = c0 + NC - 1;

    const int t  = threadIdx.x;
    const int tr = t >> 5, tc = t & 31;
    const int h  = h0 + tr, w = w0 + tc;
    const int hw = h * WW + w;

    const __half* xbase = xT + (size_t)b * HWSZ * CC + half * 32;

    // ---- issue all per-k param loads FIRST (latency hides under staging+barrier) ----
    const float* offb  = offset + (size_t)b * 2 * KK2 * HWSZ + hw;
    const float* maskb = mask   + (size_t)b * KK2 * HWSZ + hw;

    float offy[KK2], offx[KK2], mv[KK2];
#pragma unroll
    for (int k = 0; k < KK2; ++k) {
        offy[k] = offb[(2 * k)     * HWSZ];
        offx[k] = offb[(2 * k + 1) * HWSZ];
    }
#pragma unroll
    for (int k = 0; k < KK2; ++k) {
        mv[k] = maskb[k * HWSZ] * weight[k];
    }

    // ---- stage window: 4 quads (64 B) per px slot ----
    for (int idx = t; idx < NRC; idx += NTHR) {
        int r = idx / NC, c = idx - NC * r;
        int rs = min(max(r0 + r, 0), HH - 1);
        int cs = min(max(c0 + c, 0), WW - 1);
        const H8* src = (const H8*)(xbase + (size_t)(rs * WW + cs) * CC);
#pragma unroll
        for (int u = 0; u < 4; ++u)
            *(H8*)&smem[(u * PSTRIDE + idx) * 8] = src[u];
    }

    float acc[32];
#pragma unroll
    for (int i = 0; i < 32; ++i) acc[i] = 0.f;

    __syncthreads();

#pragma unroll
    for (int ki = 0; ki < 3; ++ki) {
        __half2 hacc[16];
#pragma unroll
        for (int i = 0; i < 16; ++i) hacc[i] = __floats2half2_rn(0.f, 0.f);

#pragma unroll
        for (int kj = 0; kj < 3; ++kj) {
            const int k = ki * 3 + kj;

            float py = (float)(h - 1 + ki) + offy[k];
            float px = (float)(w - 1 + kj) + offx[k];
            float y0f = floorf(py), x0f = floorf(px);
            float ly = py - y0f, lx = px - x0f;
            float hy = 1.f - ly, hx = 1.f - lx;
            int y0 = (int)y0f, x0 = (int)x0f;
            int y1 = y0 + 1,   x1 = x0 + 1;

            bool vy0 = (unsigned)y0 < (unsigned)HH;
            bool vy1 = (unsigned)y1 < (unsigned)HH;
            bool vx0 = (unsigned)x0 < (unsigned)WW;
            bool vx1 = (unsigned)x1 < (unsigned)WW;
            int y0c = min(max(y0, 0), HH - 1);
            int y1c = min(max(y1, 0), HH - 1);
            int x0c = min(max(x0, 0), WW - 1);
            int x1c = min(max(x1, 0), WW - 1);

            __half2 w00h = __float2half2_rn(hy * hx * mv[k] * (float)(vy0 && vx0));
            __half2 w01h = __float2half2_rn(hy * lx * mv[k] * (float)(vy0 && vx1));
            __half2 w10h = __float2half2_rn(ly * hx * mv[k] * (float)(vy1 && vx0));
            __half2 w11h = __float2half2_rn(ly * lx * mv[k] * (float)(vy1 && vx1));

            bool iw = (y0c >= r0) & (y1c <= r1) & (x0c >= c0) & (x1c <= c1);
            if (iw) {
                int s00 = (y0c - r0) * NC + (x0c - c0);
                int s01 = s00 + (x1c - x0c);
                int s10 = (y1c - r0) * NC + (x0c - c0);
                int s11 = s10 + (x1c - x0c);
#pragma unroll
                for (int u = 0; u < 4; ++u) {
                    const int pb = u * PSTRIDE * 8;
                    H8 v00 = *(const H8*)&smem[pb + s00 * 8];
                    H8 v01 = *(const H8*)&smem[pb + s01 * 8];
                    H8 v10 = *(const H8*)&smem[pb + s10 * 8];
                    H8 v11 = *(const H8*)&smem[pb + s11 * 8];
#pragma unroll
                    for (int q = 0; q < 4; ++q) {
                        __half2 a = hacc[u * 4 + q];
                        a = __hfma2(w00h, v00.h[q], a);
                        a = __hfma2(w01h, v01.h[q], a);
                        a = __hfma2(w10h, v10.h[q], a);
                        a = __hfma2(w11h, v11.h[q], a);
                        hacc[u * 4 + q] = a;
                    }
                }
            } else {
                const H8* g00 = (const H8*)(xbase + (size_t)(y0c * WW + x0c) * CC);
                const H8* g01 = (const H8*)(xbase + (size_t)(y0c * WW + x1c) * CC);
                const H8* g10 = (const H8*)(xbase + (size_t)(y1c * WW + x0c) * CC);
                const H8* g11 = (const H8*)(xbase + (size_t)(y1c * WW + x1c) * CC);
#pragma unroll
                for (int u = 0; u < 4; ++u) {
                    H8 v00 = g00[u];
                    H8 v01 = g01[u];
                    H8 v10 = g10[u];
                    H8 v11 = g11[u];
#pragma unroll
                    for (int q = 0; q < 4; ++q) {
                        __half2 a = hacc[u * 4 + q];
                        a = __hfma2(w00h, v00.h[q], a);
                        a = __hfma2(w01h, v01.h[q], a);
                        a = __hfma2(w10h, v10.h[q], a);
                        a = __hfma2(w11h, v11.h[q], a);
                        hacc[u * 4 + q] = a;
                    }
                }
            }
        }

        // flush the 3-k group to f32
#pragma unroll
        for (int i = 0; i < 16; ++i) {
            float2 f = __half22float2(hacc[i]);
            acc[2 * i]     += f.x;
            acc[2 * i + 1] += f.y;
        }
    }

    float* ob = out + ((size_t)b * CC + half * 32) * HWSZ + hw;
#pragma unroll
    for (int i = 0; i < 32; ++i) ob[i * HWSZ] = acc[i];
}

// ---------------- fallback (NCHW direct) ----------------
__global__ __launch_bounds__(256, 4) void dcn_kernel(
    const float* __restrict__ x,
    const float* __restrict__ offset,
    const float* __restrict__ mask,
    const float* __restrict__ weight,
    float* __restrict__ out)
{
    const int w   = threadIdx.x;
    const int row = blockIdx.x;
    const int h   = row & (HH - 1);
    const int b   = row >> 8;
    const int c0  = blockIdx.y * 16;
    const int hw  = h * WW + w;

    const float* offb  = offset + (size_t)b * 2 * KK2 * HWSZ + hw;
    const float* maskb = mask   + (size_t)b * KK2 * HWSZ + hw;
    const float* xb0   = x      + ((size_t)b * CC + c0) * HWSZ;

    float acc[16];
#pragma unroll
    for (int c = 0; c < 16; ++c) acc[c] = 0.f;

    for (int k = 0; k < KK2; ++k) {
        const int ki = k / 3;
        const int kj = k - 3 * ki;
        float offy = offb[(2 * k)     * HWSZ];
        float offx = offb[(2 * k + 1) * HWSZ];
        float mval = maskb[k * HWSZ] * weight[k];

        float py = (float)(h - 1 + ki) + offy;
        float px = (float)(w - 1 + kj) + offx;
        float y0f = floorf(py), x0f = floorf(px);
        float ly = py - y0f, lx = px - x0f;
        float hy = 1.f - ly, hx = 1.f - lx;
        int y0 = (int)y0f, x0 = (int)x0f;
        int y1 = y0 + 1,   x1 = x0 + 1;

        bool vy0 = (unsigned)y0 < (unsigned)HH;
        bool vy1 = (unsigned)y1 < (unsigned)HH;
        bool vx0 = (unsigned)x0 < (unsigned)WW;
        bool vx1 = (unsigned)x1 < (unsigned)WW;
        int y0c = min(max(y0, 0), HH - 1);
        int y1c = min(max(y1, 0), HH - 1);
        int x0c = min(max(x0, 0), WW - 1);
        int x1c = min(max(x1, 0), WW - 1);

        float w00 = hy * hx * mval * (float)(vy0 && vx0);
        float w01 = hy * lx * mval * (float)(vy0 && vx1);
        float w10 = ly * hx * mval * (float)(vy1 && vx0);
        float w11 = ly * lx * mval * (float)(vy1 && vx1);

        int i00 = y0c * WW + x0c;
        int i01 = y0c * WW + x1c;
        int i10 = y1c * WW + x0c;
        int i11 = y1c * WW + x1c;

        const float* xb = xb0;
#pragma unroll
        for (int c = 0; c < 16; ++c) {
            acc[c] = fmaf(w00, xb[i00],
                     fmaf(w01, xb[i01],
                     fmaf(w10, xb[i10],
                     fmaf(w11, xb[i11], acc[c]))));
            xb += HWSZ;
        }
    }

    float* ob = out + ((size_t)b * CC + c0) * HWSZ + hw;
#pragma unroll
    for (int c = 0; c < 16; ++c) ob[c * HWSZ] = acc[c];
}

extern "C" void kernel_launch(void* const* d_in, const int* in_sizes, int n_in,
                              void* d_out, int out_size, void* d_ws, size_t ws_size,
                              hipStream_t stream) {
    const float* x      = (const float*)d_in[0];
    const float* offset = (const float*)d_in[1];
    const float* mask   = (const float*)d_in[2];
    const float* weight = (const float*)d_in[3];
    float* out = (float*)d_out;

    const size_t xT_bytes = (size_t)BB * CC * HWSZ * sizeof(__half);
    if (ws_size >= xT_bytes) {
        __half* xT = (__half*)d_ws;
        dim3 tgrid(BB * HH, WW / 64);
        transpose_nchw_to_nhwc_f16<<<tgrid, 256, 0, stream>>>(x, xT);
        dcn_lds<<<BB * (HH / TH) * (WW / TW) * 2, NTHR, 0, stream>>>(
            xT, offset, mask, weight, out);
    } else {
        dim3 grid(BB * HH, CC / 16);
        dcn_kernel<<<grid, 256, 0, stream>>>(x, offset, mask, weight, out);
    }
}

// Round 15
// 54.096 us; speedup vs baseline: 1.2139x; 1.2139x over previous
//
#include <hip/hip_runtime.h>
#include <hip/hip_fp16.h>

#define HH 256
#define WW 256
#define CC 64
#define BB 2
#define KK2 9
#define HWSZ (HH * WW)

#define TH 8
#define TW 32
#define NR 18                 // window rows [h0-5, h0+12]
#define NC 46                 // window cols [w0-6, w0+39] (even base -> float2-aligned staging)
#define NRC (NR * NC)         // 828 slots
#define PSTRIDE (NRC + 1)     // +1 16B-slot pad between the 4 channel-octet planes
#define NSEG (32 * NR)        // 576 (channel,row) segments per block
#define TOT2 (NSEG * 23)      // 13248 float2 elements staged per block

struct __align__(16) H8 { __half2 h[4]; };   // 8 halves = 16 B

// ---------------- fused: stage NCHW f32 -> f16 LDS window, bilinear gather ----------------
// 1024 blocks x 256 threads. Block = 8x32 px x 32 ch (c-half). Window 18x46 fp16
// in LDS (53.0 KB, 3 blocks/CU). No transpose prepass: staging reads aligned
// float2 row-segments of x and converts to f16 in LDS (saves the 34 MB xT HBM
// round-trip + a ~6us dispatch). Param loads hoisted pre-staging (R13 win).
// k-loop: ds_read_b128 + v_pk_fma_f16; f32 flush per kernel row. NT stores.
__global__ __launch_bounds__(256, 2) void dcn_fused(
    const float* __restrict__ x,
    const float* __restrict__ offset,
    const float* __restrict__ mask,
    const float* __restrict__ weight,
    float* __restrict__ out)
{
    __shared__ __half smem[4 * PSTRIDE * 8];   // 53056 B

    const int nb = BB * (HH / TH) * (WW / TW) * 2;   // 1024
    int flat = blockIdx.x;
    int sb = (flat & 7) * (nb >> 3) + (flat >> 3);   // XCD-chunked, row-band sequential
    const int half = sb & 1;
    const int tw   = (sb >> 1) & 7;
    const int th   = (sb >> 4) & 31;
    const int b    = sb >> 9;

    const int h0 = th * TH, w0 = tw * TW;
    const int r0 = h0 - 5, c0 = w0 - 6;
    const int r1 = r0 + NR - 1, c1 = c0 + NC - 1;

    const int t  = threadIdx.x;
    const int tr = t >> 5, tc = t & 31;
    const int h  = h0 + tr, w = w0 + tc;
    const int hw = h * WW + w;

    // ---- issue all per-k param loads FIRST (latency hides under staging) ----
    const float* offb  = offset + (size_t)b * 2 * KK2 * HWSZ + hw;
    const float* maskb = mask   + (size_t)b * KK2 * HWSZ + hw;

    float offy[KK2], offx[KK2], mv[KK2];
#pragma unroll
    for (int k = 0; k < KK2; ++k) {
        offy[k] = offb[(2 * k)     * HWSZ];
        offx[k] = offb[(2 * k + 1) * HWSZ];
    }
#pragma unroll
    for (int k = 0; k < KK2; ++k) {
        mv[k] = maskb[k * HWSZ] * weight[k];
    }

    // ---- fused staging: NCHW f32 -> f16 window in LDS ----
    // flattened index g over (c_ch 0..31, r 0..17, c2 0..22); per-thread walk
    // g = t, t+256, ... with incremental (c_ch, r, c2) bookkeeping (no divs in loop).
    const float* xsrc = x + ((size_t)b * CC + half * 32) * HWSZ;
    {
        int g    = t;
        int seg0 = t / 23;            // <= 11, so c_ch starts at 0
        int c2   = t - seg0 * 23;
        int c_ch = 0;
        int r    = seg0;
        while (g < TOT2) {
            int rs = min(max(r0 + r, 0), HH - 1);
            const float* rowp = xsrc + (size_t)c_ch * HWSZ + rs * WW;
            int cs0 = c0 + 2 * c2;                       // even
            int cb  = min(max(cs0, 0), WW - 2);          // aligned float2 base
            float2 v = *(const float2*)(rowp + cb);
            int ja = min(max(cs0,     0), WW - 1) - cb;  // 0 or 1
            int jb = min(max(cs0 + 1, 0), WW - 1) - cb;  // 0 or 1
            float e0 = ja ? v.y : v.x;
            float e1 = jb ? v.y : v.x;
            int u = c_ch >> 3, o = c_ch & 7;
            int idx0 = r * NC + 2 * c2;
            smem[(u * PSTRIDE + idx0) * 8 + o]     = __float2half(e0);
            smem[(u * PSTRIDE + idx0 + 1) * 8 + o] = __float2half(e1);
            g += 256;
            c2 += 3; r += 11;
            if (c2 >= 23) { c2 -= 23; r += 1; }
            if (r >= NR)  { r -= NR; c_ch += 1; }
        }
    }

    float acc[32];
#pragma unroll
    for (int i = 0; i < 32; ++i) acc[i] = 0.f;

    __syncthreads();

#pragma unroll
    for (int ki = 0; ki < 3; ++ki) {
        __half2 hacc[16];
#pragma unroll
        for (int i = 0; i < 16; ++i) hacc[i] = __floats2half2_rn(0.f, 0.f);

#pragma unroll
        for (int kj = 0; kj < 3; ++kj) {
            const int k = ki * 3 + kj;

            float py = (float)(h - 1 + ki) + offy[k];
            float px = (float)(w - 1 + kj) + offx[k];
            float y0f = floorf(py), x0f = floorf(px);
            float ly = py - y0f, lx = px - x0f;
            float hy = 1.f - ly, hx = 1.f - lx;
            int y0 = (int)y0f, x0 = (int)x0f;
            int y1 = y0 + 1,   x1 = x0 + 1;

            bool vy0 = (unsigned)y0 < (unsigned)HH;
            bool vy1 = (unsigned)y1 < (unsigned)HH;
            bool vx0 = (unsigned)x0 < (unsigned)WW;
            bool vx1 = (unsigned)x1 < (unsigned)WW;
            int y0c = min(max(y0, 0), HH - 1);
            int y1c = min(max(y1, 0), HH - 1);
            int x0c = min(max(x0, 0), WW - 1);
            int x1c = min(max(x1, 0), WW - 1);

            float w00 = hy * hx * mv[k] * (float)(vy0 && vx0);
            float w01 = hy * lx * mv[k] * (float)(vy0 && vx1);
            float w10 = ly * hx * mv[k] * (float)(vy1 && vx0);
            float w11 = ly * lx * mv[k] * (float)(vy1 && vx1);

            bool iw = (y0c >= r0) & (y1c <= r1) & (x0c >= c0) & (x1c <= c1);
            if (iw) {
                __half2 w00h = __float2half2_rn(w00);
                __half2 w01h = __float2half2_rn(w01);
                __half2 w10h = __float2half2_rn(w10);
                __half2 w11h = __float2half2_rn(w11);
                int s00 = (y0c - r0) * NC + (x0c - c0);
                int s01 = s00 + (x1c - x0c);
                int s10 = (y1c - r0) * NC + (x0c - c0);
                int s11 = s10 + (x1c - x0c);
#pragma unroll
                for (int u = 0; u < 4; ++u) {
                    const int pb = u * PSTRIDE * 8;
                    H8 v00 = *(const H8*)&smem[pb + s00 * 8];
                    H8 v01 = *(const H8*)&smem[pb + s01 * 8];
                    H8 v10 = *(const H8*)&smem[pb + s10 * 8];
                    H8 v11 = *(const H8*)&smem[pb + s11 * 8];
#pragma unroll
                    for (int q = 0; q < 4; ++q) {
                        __half2 a = hacc[u * 4 + q];
                        a = __hfma2(w00h, v00.h[q], a);
                        a = __hfma2(w01h, v01.h[q], a);
                        a = __hfma2(w10h, v10.h[q], a);
                        a = __hfma2(w11h, v11.h[q], a);
                        hacc[u * 4 + q] = a;
                    }
                }
            } else {
                // rare Gaussian-tail fallback: read x (f32) directly, accumulate in f32
                int i00 = y0c * WW + x0c;
                int i01 = y0c * WW + x1c;
                int i10 = y1c * WW + x0c;
                int i11 = y1c * WW + x1c;
#pragma unroll
                for (int i = 0; i < 32; ++i) {
                    const float* p = xsrc + (size_t)i * HWSZ;
                    acc[i] += w00 * p[i00] + w01 * p[i01] + w10 * p[i10] + w11 * p[i11];
                }
            }
        }

        // flush the 3-k group to f32
#pragma unroll
        for (int i = 0; i < 16; ++i) {
            float2 f = __half22float2(hacc[i]);
            acc[2 * i]     += f.x;
            acc[2 * i + 1] += f.y;
        }
    }

    float* ob = out + ((size_t)b * CC + half * 32) * HWSZ + hw;
#pragma unroll
    for (int i = 0; i < 32; ++i)
        __builtin_nontemporal_store(acc[i], &ob[i * HWSZ]);
}

extern "C" void kernel_launch(void* const* d_in, const int* in_sizes, int n_in,
                              void* d_out, int out_size, void* d_ws, size_t ws_size,
                              hipStream_t stream) {
    const float* x      = (const float*)d_in[0];
    const float* offset = (const float*)d_in[1];
    const float* mask   = (const float*)d_in[2];
    const float* weight = (const float*)d_in[3];
    float* out = (float*)d_out;

    dcn_fused<<<BB * (HH / TH) * (WW / TW) * 2, 256, 0, stream>>>(
        x, offset, mask, weight, out);
}